// Round 15
// baseline (575.928 us; speedup 1.0000x reference)
//
#include <hip/hip_runtime.h>
#include <cstdint>
#include <cstddef>

typedef __attribute__((ext_vector_type(8))) short bf16x8;
typedef __attribute__((ext_vector_type(8))) unsigned short ushort8;
typedef __attribute__((ext_vector_type(4))) float f32x4;

__device__ __forceinline__ unsigned short f2bf(float f){
  unsigned int u = __float_as_uint(f);
  unsigned int lsb = (u >> 16) & 1u;
  u += 0x7fffu + lsb;
  return (unsigned short)(u >> 16);
}

__device__ __forceinline__ ushort8 cvt8(const float4 a, const float4 b){
  ushort8 u; u[0]=f2bf(a.x); u[1]=f2bf(a.y); u[2]=f2bf(a.z); u[3]=f2bf(a.w);
  u[4]=f2bf(b.x); u[5]=f2bf(b.y); u[6]=f2bf(b.z); u[7]=f2bf(b.w); return u;
}

__device__ __forceinline__ void gload16(const void* g, void* l){
  __builtin_amdgcn_global_load_lds(
      (const __attribute__((address_space(1))) unsigned int*)g,
      (__attribute__((address_space(3))) unsigned int*)l, 16, 0, 0);
}

// ---------------- weight packing ----------------
__global__ __launch_bounds__(256) void pack_w_bf16_kernel(const float* __restrict__ W,
    unsigned short* __restrict__ Wb, int COUT, int CIN){
  int idx = blockIdx.x*256 + threadIdx.x;
  int tot = COUT*CIN*3;
  if (idx >= tot) return;
  int o = idx/(CIN*3); int r = idx - o*(CIN*3); int kk = r/CIN; int ci = r - kk*CIN;
  Wb[idx] = f2bf(W[(o*CIN + ci)*3 + kk]);
}

// Bh[p][i] = Wp[p,i,1] bf16 (h0's K=64 GEMM B-matrix)
__global__ __launch_bounds__(256) void pack_bh_kernel(const float* __restrict__ Wp,
                                                      unsigned short* __restrict__ Bh){
  int idx = blockIdx.x*256 + threadIdx.x;
  if (idx >= 64*64) return;
  int p = idx >> 6, i = idx & 63;
  Bh[idx] = f2bf(Wp[p*128 + i*2 + 1]);
}

__global__ __launch_bounds__(256) void f2bf_kernel(const float* __restrict__ src,
                                                   unsigned short* __restrict__ dst, int n){
  int i = blockIdx.x*256 + threadIdx.x;
  if (i < n) dst[i] = f2bf(src[i]);
}

// zero guard rows 0 and LINP-1 of each padded batch
__global__ __launch_bounds__(256) void zero_guards_kernel(unsigned short* __restrict__ buf,
                                                          int LINP, int CIN, int nb){
  int idx = blockIdx.x*256 + threadIdx.x;
  int per = 2*CIN/8;
  if (idx >= nb*per) return;
  int b = idx / per, r = idx - b*per;
  int g = r / (CIN/8), c8 = r - g*(CIN/8);
  ushort8 z = {0,0,0,0,0,0,0,0};
  *(ushort8*)(buf + ((size_t)b*LINP + (size_t)g*(LINP-1))*CIN + c8*8) = z;
}

// ---------------- branch MLP -> Hcat[16384:] ----------------
__global__ __launch_bounds__(256) void branch_kernel(const float* __restrict__ x,
    const float* __restrict__ Wb1, const float* __restrict__ bb1,
    const float* __restrict__ Wb2, const float* __restrict__ bb2,
    const float* __restrict__ Wb3, const float* __restrict__ bb3,
    unsigned short* __restrict__ Hcat){
  __shared__ float s0[64], s1[64], s2[128];
  const int b = blockIdx.x, tid = threadIdx.x;
  const float* xb = x + (size_t)b*16384;
  if (tid < 64) s0[tid] = xb[tid];
  __syncthreads();
  if (tid < 64){
    float a = bb1[tid];
    for (int k=0;k<64;k++) a = fmaf(Wb1[tid*64+k], s0[k], a);
    s1[tid] = fmaxf(a, 0.f);
  }
  __syncthreads();
  if (tid < 128){
    float a = bb2[tid];
    for (int k=0;k<64;k++) a = fmaf(Wb2[tid*64+k], s1[k], a);
    s2[tid] = fmaxf(a, 0.f);
  }
  __syncthreads();
  float a = bb3[tid];
  for (int k=0;k<128;k++) a = fmaf(Wb3[tid*128+k], s2[k], a);
  Hcat[(size_t)b*16640 + 16384 + tid] = f2bf(fmaxf(a, 0.f));
}

// ---------------- F1: per-batch x -> h0 -> conv1 -> padded buf2 [b][257][128] ----------------
// (validated structure from R6; only the epilogue layout changed)
__global__ __launch_bounds__(512) void fused1_kernel(
    const float* __restrict__ x, const float* __restrict__ Wp, const float* __restrict__ bp,
    const unsigned short* __restrict__ Bh, const unsigned short* __restrict__ W1b,
    const float* __restrict__ b1, unsigned short* __restrict__ c1p){
  __shared__ __align__(16) char S[115392];
  constexpr int SX = 0;          // 257*144
  constexpr int SH = 37008;      // 258*144
  constexpr int SB = 74160;      // 2*16384
  constexpr int SW = 106928;     // 8192
  constexpr int SY = 115120;     // 256
  const int b = blockIdx.x, tid = threadIdx.x;
  const int lane = tid & 63, wv = tid >> 6;
  const int lr = lane & 15, lg = lane >> 4;
  const float* xg = x + (size_t)b*16384;

  // --- phase A0: stage x (bf16), Bh, zeros, y0 ---
  #pragma unroll
  for (int i=0;i<4;i++){
    int s = tid + 512*i;
    int row = s>>3, sl = s&7;
    const float4* src = (const float4*)(xg + row*64 + sl*8);
    *(ushort8*)(S + SX + row*144 + sl*16) = cvt8(src[0], src[1]);
  }
  { int row = tid>>3, sl = tid&7;
    ushort8 u = *(const ushort8*)(Bh + row*64 + sl*8);
    *(ushort8*)(S + SW + row*128 + ((sl*16)^((row&7)<<4))) = u; }
  ushort8 z8 = {0,0,0,0,0,0,0,0};
  if (tid < 9)        *(ushort8*)(S + SX + 256*144 + tid*16) = z8;
  else if (tid < 18)  *(ushort8*)(S + SH + 0*144   + (tid-9)*16) = z8;
  else if (tid < 27)  *(ushort8*)(S + SH + 257*144 + (tid-18)*16) = z8;
  if (tid < 64){
    float a = bp[tid];
    const float* wr = Wp + tid*128;
    #pragma unroll 8
    for (int i=0;i<64;i++) a = fmaf(wr[2*i], xg[i], a);
    *(float*)(S + SY + tid*4) = a;
  }
  __syncthreads();

  // --- phase A1: h0 GEMM (M=256 pad, N=64, K=64) -> sH rows 1..255 ---
  {
    const int wm = wv>>1, wn = wv&1;
    f32x4 acc[4][2];
    #pragma unroll
    for (int i=0;i<4;i++){ acc[i][0]=(f32x4){0,0,0,0}; acc[i][1]=(f32x4){0,0,0,0}; }
    #pragma unroll
    for (int ks=0; ks<2; ks++){
      int k = ks*32 + lg*8;
      bf16x8 af[4], bf[2];
      #pragma unroll
      for (int f=0;f<4;f++){ int ar = wm*64 + f*16 + lr + 1;
        af[f] = *(const bf16x8*)(S + SX + ar*144 + k*2); }
      #pragma unroll
      for (int f=0;f<2;f++){ int rb = wn*32 + f*16 + lr;
        bf[f] = *(const bf16x8*)(S + SW + rb*128 + ((k*2)^((rb&7)<<4))); }
      #pragma unroll
      for (int i=0;i<4;i++)
        #pragma unroll
        for (int j=0;j<2;j++)
          acc[i][j] = __builtin_amdgcn_mfma_f32_16x16x32_bf16(af[i], bf[j], acc[i][j], 0,0,0);
    }
    #pragma unroll
    for (int fm=0;fm<4;fm++)
      #pragma unroll
      for (int fn=0;fn<2;fn++)
        #pragma unroll
        for (int j=0;j<4;j++){
          int t = wm*64 + fm*16 + lg*4 + j;
          int p = wn*32 + fn*16 + lr;
          float v = acc[fm][fn][j] + *(const float*)(S + SY + p*4);
          unsigned short o = (t < 255) ? f2bf(fmaxf(v, 0.f)) : (unsigned short)0;
          *(unsigned short*)(S + SH + (t+1)*144 + p*2) = o;
        }
  }

  // --- phase B: conv1 (M=256 pad, N=128, K=192, 3 chunks, dbuf gload) ---
  {
    const int soff = ((lane&7)^(lane>>3))<<3;
    const int rbase = wv*8 + (lane>>3);
    #pragma unroll
    for (int s=0;s<2;s++)
      gload16(W1b + (size_t)(s*64 + rbase)*192 + soff, S + SB + s*8192 + wv*1024);
    __syncthreads();   // sH writes + buf0 ready

    const int wm = wv>>1, wn = wv&1;
    f32x4 acc[4][4];
    #pragma unroll
    for (int i=0;i<4;i++)
      #pragma unroll
      for (int j=0;j<4;j++) acc[i][j] = (f32x4){0,0,0,0};
    #pragma unroll
    for (int c=0;c<3;c++){
      int buf = c&1;
      if (c<2){
        #pragma unroll
        for (int s=0;s<2;s++)
          gload16(W1b + (size_t)(s*64 + rbase)*192 + (c+1)*64 + soff,
                  S + SB + (buf^1)*16384 + s*8192 + wv*1024);
      }
      #pragma unroll
      for (int ks=0; ks<2; ks++){
        int k = ks*32 + lg*8;
        bf16x8 af[4], bf[4];
        #pragma unroll
        for (int f=0;f<4;f++){ int ar = wm*64 + f*16 + lr + c;
          af[f] = *(const bf16x8*)(S + SH + ar*144 + k*2); }
        #pragma unroll
        for (int f=0;f<4;f++){ int rb = wn*64 + f*16 + lr;
          bf[f] = *(const bf16x8*)(S + SB + buf*16384 + rb*128 + ((k*2)^((rb&7)<<4))); }
        #pragma unroll
        for (int i=0;i<4;i++)
          #pragma unroll
          for (int j=0;j<4;j++)
            acc[i][j] = __builtin_amdgcn_mfma_f32_16x16x32_bf16(af[i], bf[j], acc[i][j], 0,0,0);
      }
      __syncthreads();
    }
    // write conv1 out into PADDED [b][257][128], data rows 1..255
    unsigned short* cbo = c1p + (size_t)b*32896;
    #pragma unroll
    for (int fi=0;fi<4;fi++)
      #pragma unroll
      for (int fj=0;fj<4;fj++)
        #pragma unroll
        for (int j=0;j<4;j++){
          int t = wm*64 + fi*16 + lg*4 + j;
          int n = wn*64 + fj*16 + lr;
          if (t < 255) cbo[(size_t)(t+1)*128 + n] = f2bf(fmaxf(acc[fi][fj][j] + b1[n], 0.f));
        }
  }
}

// ---------------- conv1d as plain GEMM over padded activations (dbuf K-pipeline) ----------------
template<int CIN,int COUT,int S,int LINP,int LOUT,bool TO_HCAT>
__global__ __launch_bounds__(256) void conv_gemm_kernel(
    const unsigned short* __restrict__ in, const unsigned short* __restrict__ Wb,
    const float* __restrict__ bias, unsigned short* __restrict__ out){
  constexpr int K = 3*CIN;
  constexpr int KS = K/64;
  __shared__ __align__(16) char sA[2*128*128];
  __shared__ __align__(16) char sB[2*128*128];
  const int tid = threadIdx.x;
  int m0;
  {
    int bid = blockIdx.x, nwg = gridDim.x;
    if ((nwg & 7) == 0){ int q = nwg >> 3; m0 = ((bid & 7)*q + (bid >> 3))*128; }
    else m0 = bid*128;
  }
  const int n0 = blockIdx.y*128;
  const int lane = tid & 63, wid = tid >> 6;
  const int wm = wid >> 1, wn = wid & 1;
  const int lr = lane & 15, lg = lane >> 4;
  const int srow = lane >> 3;
  const int soff = (((lane&7) ^ srow) << 3);
  const unsigned short* abase[4];
  const unsigned short* bbase[4];
  #pragma unroll
  for (int s=0;s<4;s++){
    int row = wid*32 + s*8 + srow;
    int m = m0 + row;
    int b = m / LOUT, t = m - b*LOUT;
    abase[s] = in + ((size_t)b*LINP + (size_t)t*S)*CIN + soff;
    bbase[s] = Wb + (size_t)(n0+row)*K + soff;
  }
  f32x4 acc[4][4];
  #pragma unroll
  for (int i=0;i<4;i++)
    #pragma unroll
    for (int j=0;j<4;j++) acc[i][j] = (f32x4){0,0,0,0};

  auto stage = [&](int ks, int bufi){
    const int k0 = ks*64;
    #pragma unroll
    for (int s=0;s<4;s++){
      gload16(abase[s] + k0, sA + bufi*16384 + wid*4096 + s*1024);
      gload16(bbase[s] + k0, sB + bufi*16384 + wid*4096 + s*1024);
    }
  };
  stage(0, 0);
  __syncthreads();
  int buf = 0;
  #pragma unroll
  for (int ks=0; ks<KS; ks++){
    if (ks+1 < KS) stage(ks+1, buf^1);
    #pragma unroll
    for (int kss=0; kss<2; kss++){
      const int k = kss*32 + lg*8;
      bf16x8 af[4], bfr[4];
      #pragma unroll
      for (int f=0;f<4;f++){
        int ra = wm*64 + f*16 + lr;
        af[f]  = *(const bf16x8*)(sA + buf*16384 + ra*128 + ((k*2) ^ ((ra&7)<<4)));
        int rb = wn*64 + f*16 + lr;
        bfr[f] = *(const bf16x8*)(sB + buf*16384 + rb*128 + ((k*2) ^ ((rb&7)<<4)));
      }
      #pragma unroll
      for (int fi=0;fi<4;fi++)
        #pragma unroll
        for (int fj=0;fj<4;fj++)
          acc[fi][fj] = __builtin_amdgcn_mfma_f32_16x16x32_bf16(af[fi], bfr[fj], acc[fi][fj], 0,0,0);
    }
    __syncthreads();
    buf ^= 1;
  }
  #pragma unroll
  for (int fi=0;fi<4;fi++)
    #pragma unroll
    for (int fj=0;fj<4;fj++)
      #pragma unroll
      for (int j=0;j<4;j++){
        int m = m0 + wm*64 + fi*16 + lg*4 + j;
        int n = n0 + wn*64 + fj*16 + lr;
        int b = m / LOUT, t = m - b*LOUT;
        float val = fmaxf(acc[fi][fj][j] + bias[n], 0.f);
        if (TO_HCAT) out[(size_t)b*16640 + (size_t)n*64 + t] = f2bf(val);
        else         out[((size_t)b*(LOUT+2) + t + 1)*COUT + n] = f2bf(val);
      }
}

// ---------------- fc1: bf16 MFMA GEMM, K-split KZ, XCD-grouped, dbuf K-pipeline ----------------
__global__ __launch_bounds__(256) void fc1_gemm_kernel(
    const unsigned short* __restrict__ A, const unsigned short* __restrict__ Bw,
    float* __restrict__ zp, int zoffm, int MT, int KZ){
  __shared__ __align__(16) char sA[2*128*128];
  __shared__ __align__(16) char sB[2*128*128];
  const int tid = threadIdx.x;
  const int nwg = gridDim.x;
  const int lgid = (blockIdx.x % 8)*(nwg/8) + blockIdx.x/8;
  const int kz  = lgid / (8*MT);
  const int rem = lgid % (8*MT);
  const int nt  = rem / MT;
  const int mt  = rem % MT;
  const int n0 = nt*128, m0 = mt*128;
  const int lane = tid & 63, wid = tid >> 6;
  const int wm = wid >> 1, wn = wid & 1;
  const int lr = lane & 15, lg = lane >> 4;
  const int srow = lane >> 3;
  const int soff = (((lane&7) ^ srow) << 3);
  f32x4 acc[4][4];
  #pragma unroll
  for (int i=0;i<4;i++)
    #pragma unroll
    for (int j=0;j<4;j++) acc[i][j] = (f32x4){0,0,0,0};
  const int it0 = (kz*260)/KZ, it1 = ((kz+1)*260)/KZ;

  auto stage = [&](int it, int bufi){
    const size_t k0 = (size_t)it*64;
    #pragma unroll
    for (int s=0;s<4;s++){
      int row = wid*32 + s*8 + srow;
      gload16(A  + (size_t)(m0+row)*16640 + k0 + soff, sA + bufi*16384 + wid*4096 + s*1024);
      gload16(Bw + (size_t)(n0+row)*16640 + k0 + soff, sB + bufi*16384 + wid*4096 + s*1024);
    }
  };
  stage(it0, 0);
  __syncthreads();
  int buf = 0;
  for (int it=it0; it<it1; ++it){
    if (it+1 < it1) stage(it+1, buf^1);
    #pragma unroll
    for (int ks=0; ks<2; ks++){
      const int k = ks*32 + lg*8;
      bf16x8 af[4], bfr[4];
      #pragma unroll
      for (int f=0;f<4;f++){
        int rowa = wm*64 + f*16 + lr;
        af[f]  = *(const bf16x8*)(sA + buf*16384 + rowa*128 + ((k*2) ^ ((rowa&7)<<4)));
        int rowb = wn*64 + f*16 + lr;
        bfr[f] = *(const bf16x8*)(sB + buf*16384 + rowb*128 + ((k*2) ^ ((rowb&7)<<4)));
      }
      #pragma unroll
      for (int fi=0;fi<4;fi++)
        #pragma unroll
        for (int fj=0;fj<4;fj++)
          acc[fi][fj] = __builtin_amdgcn_mfma_f32_16x16x32_bf16(af[fi], bfr[fj], acc[fi][fj], 0,0,0);
    }
    __syncthreads();
    buf ^= 1;
  }
  float* zo = zp + (size_t)kz*zoffm;
  #pragma unroll
  for (int fi=0;fi<4;fi++)
    #pragma unroll
    for (int fj=0;fj<4;fj++)
      #pragma unroll
      for (int j=0;j<4;j++){
        int m = m0 + wm*64 + fi*16 + lg*4 + j;
        int n = n0 + wn*64 + fj*16 + lr;
        zo[(size_t)m*1024 + n] = acc[fi][fj][j];
      }
}

// ---------------- fc2 ----------------
__global__ __launch_bounds__(256) void fc2_kernel(const float* __restrict__ zp, int zoffm, int KZ,
    const float* __restrict__ bfc1, const float* __restrict__ Wfc2,
    const float* __restrict__ bfc2, float* __restrict__ out){
  __shared__ float red[4][2];
  const int b = blockIdx.x, tid = threadIdx.x;
  float a0 = 0.f, a1 = 0.f;
  for (int n = tid; n < 1024; n += 256){
    float s = bfc1[n];
    const float* zb = zp + (size_t)b*1024 + n;
    for (int kz = 0; kz < KZ; kz++) s += zb[(size_t)kz*zoffm];
    s = fmaxf(s, 0.f);
    a0 = fmaf(s, Wfc2[n], a0);
    a1 = fmaf(s, Wfc2[1024+n], a1);
  }
  #pragma unroll
  for (int m=32; m>=1; m>>=1){ a0 += __shfl_xor(a0, m, 64); a1 += __shfl_xor(a1, m, 64); }
  const int w = tid >> 6;
  if ((tid & 63) == 0){ red[w][0] = a0; red[w][1] = a1; }
  __syncthreads();
  if (tid == 0){
    out[(size_t)b*2]   = red[0][0]+red[1][0]+red[2][0]+red[3][0] + bfc2[0];
    out[(size_t)b*2+1] = red[0][1]+red[1][1]+red[2][1]+red[3][1] + bfc2[1];
  }
}

extern "C" void kernel_launch(void* const* d_in, const int* in_sizes, int n_in,
                              void* d_out, int out_size, void* d_ws, size_t ws_size,
                              hipStream_t stream){
  const float* x    = (const float*)d_in[0];
  const float* Wp   = (const float*)d_in[1];
  const float* bp   = (const float*)d_in[2];
  const float* W1   = (const float*)d_in[3];
  const float* b1   = (const float*)d_in[4];
  const float* W2   = (const float*)d_in[5];
  const float* b2   = (const float*)d_in[6];
  const float* W3   = (const float*)d_in[7];
  const float* b3   = (const float*)d_in[8];
  const float* Wb1  = (const float*)d_in[9];
  const float* bb1  = (const float*)d_in[10];
  const float* Wb2  = (const float*)d_in[11];
  const float* bb2  = (const float*)d_in[12];
  const float* Wb3  = (const float*)d_in[13];
  const float* bb3  = (const float*)d_in[14];
  const float* Wfc1 = (const float*)d_in[15];
  const float* bfc1 = (const float*)d_in[16];
  const float* Wfc2 = (const float*)d_in[17];
  const float* bfc2 = (const float*)d_in[18];
  float* out = (float*)d_out;

  size_t off = 0;
  char* basep = (char*)d_ws;
  auto carve = [&](size_t bytes)->char*{
    char* q = basep + off; off += (bytes + 255) & ~(size_t)255; return q;
  };
  unsigned short* W1b   = (unsigned short*)carve((size_t)128*3*64*2);
  unsigned short* W2b   = (unsigned short*)carve((size_t)256*3*128*2);
  unsigned short* W3b   = (unsigned short*)carve((size_t)256*3*256*2);
  unsigned short* Bhp   = (unsigned short*)carve((size_t)64*64*2);
  unsigned short* Wfc1b = (unsigned short*)carve((size_t)1024*16640*2);
  size_t fixed = off;

  // per-batch BYTES: buf1 (conv2out 130*256*2) = 66560 ; buf2 (conv1out 257*128*2) = 65792
  //                  Hcat 33280 ; zp KZ*4096
  int Bc = 128, KZ = 64;
  {
    const int bcs[5] = {2048, 1024, 512, 256, 128};
    const int kzs[5] = {4, 8, 16, 32, 64};
    for (int i = 0; i < 5; i++){
      size_t b = bcs[i];
      size_t need = fixed + b*((size_t)66560+65792+33280) + (size_t)kzs[i]*b*4096 + 16*256;
      if (need <= ws_size){ Bc = bcs[i]; KZ = kzs[i]; break; }
    }
  }
  const int NC = 2048/Bc;
  const int MT = Bc/128;
  unsigned short* buf1 = (unsigned short*)carve((size_t)Bc*66560);
  unsigned short* buf2 = (unsigned short*)carve((size_t)Bc*65792);
  unsigned short* Hcat = (unsigned short*)carve((size_t)Bc*33280);
  float*          zp   = (float*)carve((size_t)KZ*Bc*4096);
  const int zoffm = Bc*1024;

  hipLaunchKernelGGL(pack_w_bf16_kernel, dim3((128*64*3+255)/256), dim3(256), 0, stream, W1, W1b, 128, 64);
  hipLaunchKernelGGL(pack_w_bf16_kernel, dim3((256*128*3+255)/256), dim3(256), 0, stream, W2, W2b, 256, 128);
  hipLaunchKernelGGL(pack_w_bf16_kernel, dim3((256*256*3+255)/256), dim3(256), 0, stream, W3, W3b, 256, 256);
  hipLaunchKernelGGL(pack_bh_kernel, dim3(16), dim3(256), 0, stream, Wp, Bhp);
  hipLaunchKernelGGL(f2bf_kernel, dim3((17039360+255)/256), dim3(256), 0, stream, Wfc1, Wfc1b, 17039360);

  for (int c = 0; c < NC; ++c){
    const float* xc = x + (size_t)c*Bc*16384;
    // guards: buf2 as [Bc][257][128], buf1 as [Bc][130][256]
    hipLaunchKernelGGL(zero_guards_kernel, dim3((Bc*2*128/8+255)/256), dim3(256), 0, stream,
                       buf2, 257, 128, Bc);
    hipLaunchKernelGGL(zero_guards_kernel, dim3((Bc*2*256/8+255)/256), dim3(256), 0, stream,
                       buf1, 130, 256, Bc);
    hipLaunchKernelGGL(branch_kernel, dim3(Bc), dim3(256), 0, stream,
                       xc, Wb1, bb1, Wb2, bb2, Wb3, bb3, Hcat);
    // F1: x -> h0 -> conv1 (padded buf2)
    hipLaunchKernelGGL(fused1_kernel, dim3(Bc), dim3(512), 0, stream,
                       xc, Wp, bp, Bhp, W1b, b1, buf2);
    // conv2: 128->256, S=2, padded 257 -> padded 130x256 ; M = Bc*128
    hipLaunchKernelGGL((conv_gemm_kernel<128,256,2,257,128,false>), dim3(Bc, 2), dim3(256), 0, stream,
                       buf2, W2b, b2, buf1);
    // conv3: 256->256, S=2, padded 130 -> Hcat channel-major ; M = Bc*64
    hipLaunchKernelGGL((conv_gemm_kernel<256,256,2,130,64,true>), dim3(Bc/2, 2), dim3(256), 0, stream,
                       buf1, W3b, b3, Hcat);
    hipLaunchKernelGGL(fc1_gemm_kernel, dim3(8*MT*KZ), dim3(256), 0, stream,
                       Hcat, Wfc1b, zp, zoffm, MT, KZ);
    hipLaunchKernelGGL(fc2_kernel, dim3(Bc), dim3(256), 0, stream,
                       zp, zoffm, KZ, bfc1, Wfc2, bfc2, out + (size_t)c*Bc*2);
  }
}

// Round 16
// 547.302 us; speedup vs baseline: 1.0523x; 1.0523x over previous
//
#include <hip/hip_runtime.h>
#include <cstdint>
#include <cstddef>

typedef __attribute__((ext_vector_type(8))) short bf16x8;
typedef __attribute__((ext_vector_type(8))) unsigned short ushort8;
typedef __attribute__((ext_vector_type(4))) float f32x4;

__device__ __forceinline__ unsigned short f2bf(float f){
  unsigned int u = __float_as_uint(f);
  unsigned int lsb = (u >> 16) & 1u;
  u += 0x7fffu + lsb;
  return (unsigned short)(u >> 16);
}

// ---------------- weight packing ----------------
__global__ __launch_bounds__(256) void pack_w_bf16_kernel(const float* __restrict__ W,
    unsigned short* __restrict__ Wb, int COUT, int CIN){
  int idx = blockIdx.x*256 + threadIdx.x;
  int tot = COUT*CIN*3;
  if (idx >= tot) return;
  int o = idx/(CIN*3); int r = idx - o*(CIN*3); int kk = r/CIN; int ci = r - kk*CIN;
  Wb[idx] = f2bf(W[(o*CIN + ci)*3 + kk]);
}

__global__ __launch_bounds__(256) void pack_wp_kernel(const float* __restrict__ Wp,
                                                      unsigned short* __restrict__ Bw){
  int idx = blockIdx.x*256 + threadIdx.x;
  if (idx >= 64*128) return;
  int p = idx >> 7, k = idx & 127;
  float v = (k < 64) ? Wp[p*128 + k*2] : Wp[p*128 + (k-64)*2 + 1];
  Bw[idx] = f2bf(v);
}

__global__ __launch_bounds__(256) void f2bf_kernel(const float* __restrict__ src,
                                                   unsigned short* __restrict__ dst, int n){
  int i = blockIdx.x*256 + threadIdx.x;
  if (i < n) dst[i] = f2bf(src[i]);
}

// zero guard rows 0 and LINP-1 of each padded batch
__global__ __launch_bounds__(256) void zero_guards_kernel(unsigned short* __restrict__ buf,
                                                          int LINP, int CIN, int nb){
  int idx = blockIdx.x*256 + threadIdx.x;
  int per = 2*CIN/8;
  if (idx >= nb*per) return;
  int b = idx / per, r = idx - b*per;
  int g = r / (CIN/8), c8 = r - g*(CIN/8);
  ushort8 z = {0,0,0,0,0,0,0,0};
  *(ushort8*)(buf + ((size_t)b*LINP + (size_t)g*(LINP-1))*CIN + c8*8) = z;
}

// ---------------- branch MLP -> Hcat[16384:] ----------------
__global__ __launch_bounds__(256) void branch_kernel(const float* __restrict__ x,
    const float* __restrict__ Wb1, const float* __restrict__ bb1,
    const float* __restrict__ Wb2, const float* __restrict__ bb2,
    const float* __restrict__ Wb3, const float* __restrict__ bb3,
    unsigned short* __restrict__ Hcat){
  __shared__ float s0[64], s1[64], s2[128];
  const int b = blockIdx.x, tid = threadIdx.x;
  const float* xb = x + (size_t)b*16384;
  if (tid < 64) s0[tid] = xb[tid];
  __syncthreads();
  if (tid < 64){
    float a = bb1[tid];
    for (int k=0;k<64;k++) a = fmaf(Wb1[tid*64+k], s0[k], a);
    s1[tid] = fmaxf(a, 0.f);
  }
  __syncthreads();
  if (tid < 128){
    float a = bb2[tid];
    for (int k=0;k<64;k++) a = fmaf(Wb2[tid*64+k], s1[k], a);
    s2[tid] = fmaxf(a, 0.f);
  }
  __syncthreads();
  float a = bb3[tid];
  for (int k=0;k<128;k++) a = fmaf(Wb3[tid*128+k], s2[k], a);
  Hcat[(size_t)b*16640 + 16384 + tid] = f2bf(fmaxf(a, 0.f));
}

// ---------------- h0 GEMM -> padded [b][257][64] ----------------
__global__ __launch_bounds__(256) void h0_gemm_kernel(const float* __restrict__ x,
    const unsigned short* __restrict__ Bw, const float* __restrict__ bp,
    unsigned short* __restrict__ h0o){
  __shared__ __align__(16) char sAraw[128*256];
  __shared__ __align__(16) char sBraw[64*256];
  const int tid = threadIdx.x;
  const int m0 = blockIdx.x*128;
  #pragma unroll
  for (int i=0;i<16;i++){
    int j = tid + 256*i;
    int row = j >> 5, q = j & 31;
    int m = m0 + row;
    int b = m / 255, c = m - b*255;
    const float* xb = x + (size_t)b*16384;
    int k = q*4;
    const float* src = (k < 64) ? (xb + k) : (xb + (c+1)*64 + (k-64));
    float4 v = *(const float4*)src;
    ushort4 u; u.x=f2bf(v.x); u.y=f2bf(v.y); u.z=f2bf(v.z); u.w=f2bf(v.w);
    *(ushort4*)(sAraw + row*256 + ((k*2) ^ ((row&7)<<4))) = u;
  }
  #pragma unroll
  for (int i=0;i<4;i++){
    int j = tid + 256*i;
    int row = j >> 4, q = j & 15;
    int k = q*8;
    ushort8 u = *(const ushort8*)(Bw + row*128 + k);
    *(ushort8*)(sBraw + row*256 + ((k*2) ^ ((row&7)<<4))) = u;
  }
  __syncthreads();
  const int lane = tid & 63, wid = tid >> 6;
  const int lr = lane & 15, lg = lane >> 4;
  f32x4 acc[2][4];
  #pragma unroll
  for (int a=0;a<2;a++)
    #pragma unroll
    for (int j=0;j<4;j++) acc[a][j] = (f32x4){0,0,0,0};
  #pragma unroll
  for (int ks=0; ks<4; ks++){
    int k = ks*32 + lg*8;
    bf16x8 af[2], bfr[4];
    #pragma unroll
    for (int f=0; f<2; f++){
      int row = wid*32 + f*16 + lr;
      af[f] = *(const bf16x8*)(sAraw + row*256 + ((k*2) ^ ((row&7)<<4)));
    }
    #pragma unroll
    for (int f=0; f<4; f++){
      int row = f*16 + lr;
      bfr[f] = *(const bf16x8*)(sBraw + row*256 + ((k*2) ^ ((row&7)<<4)));
    }
    #pragma unroll
    for (int fi=0; fi<2; fi++)
      #pragma unroll
      for (int fj=0; fj<4; fj++)
        acc[fi][fj] = __builtin_amdgcn_mfma_f32_16x16x32_bf16(af[fi], bfr[fj], acc[fi][fj], 0,0,0);
  }
  #pragma unroll
  for (int fi=0; fi<2; fi++)
    #pragma unroll
    for (int fj=0; fj<4; fj++)
      #pragma unroll
      for (int j=0;j<4;j++){
        int m = m0 + wid*32 + fi*16 + lg*4 + j;
        int n = fj*16 + lr;
        int b = m / 255, t = m - b*255;
        h0o[((size_t)b*257 + t + 1)*64 + n] = f2bf(fmaxf(acc[fi][fj][j] + bp[n], 0.f));
      }
}

// ---------------- conv1d as plain GEMM, REG-STAGED (L1/L2-cached) dbuf K-pipeline ----------------
// lane loads logical 16B chunk (lane&7) linearly (coalesced), ds_writes to swizzled slot chunk^(row&7).
template<int CIN,int COUT,int S,int LINP,int LOUT,bool TO_HCAT>
__global__ __launch_bounds__(256) void conv_gemm_kernel(
    const unsigned short* __restrict__ in, const unsigned short* __restrict__ Wb,
    const float* __restrict__ bias, unsigned short* __restrict__ out){
  constexpr int K = 3*CIN;
  constexpr int KS = K/64;
  __shared__ __align__(16) char sA[2*128*128];
  __shared__ __align__(16) char sB[2*128*128];
  const int tid = threadIdx.x;
  int m0;
  {
    int bid = blockIdx.x, nwg = gridDim.x;
    if ((nwg & 7) == 0){ int q = nwg >> 3; m0 = ((bid & 7)*q + (bid >> 3))*128; }
    else m0 = bid*128;
  }
  const int n0 = blockIdx.y*128;
  const int lane = tid & 63, wid = tid >> 6;
  const int wm = wid >> 1, wn = wid & 1;
  const int lr = lane & 15, lg = lane >> 4;
  const int srow = lane >> 3;
  const int ch = lane & 7;
  const unsigned short* abase[4];
  const unsigned short* bbase[4];
  int dsto[4];
  #pragma unroll
  for (int s=0;s<4;s++){
    int row = wid*32 + s*8 + srow;
    int m = m0 + row;
    int b = m / LOUT, t = m - b*LOUT;
    abase[s] = in + ((size_t)b*LINP + (size_t)t*S)*CIN + ch*8;
    bbase[s] = Wb + (size_t)(n0+row)*K + ch*8;
    dsto[s] = row*128 + ((ch ^ srow) << 4);
  }
  f32x4 acc[4][4];
  #pragma unroll
  for (int i=0;i<4;i++)
    #pragma unroll
    for (int j=0;j<4;j++) acc[i][j] = (f32x4){0,0,0,0};

  ushort8 ra[4], rb[4];
  auto loadregs = [&](int ks){
    const int k0 = ks*64;
    #pragma unroll
    for (int s=0;s<4;s++){
      ra[s] = *(const ushort8*)(abase[s] + k0);
      rb[s] = *(const ushort8*)(bbase[s] + k0);
    }
  };
  auto writeregs = [&](int bufi){
    #pragma unroll
    for (int s=0;s<4;s++){
      *(ushort8*)(sA + bufi*16384 + dsto[s]) = ra[s];
      *(ushort8*)(sB + bufi*16384 + dsto[s]) = rb[s];
    }
  };
  loadregs(0); writeregs(0);
  if (KS > 1) loadregs(1);
  __syncthreads();
  int buf = 0;
  #pragma unroll
  for (int ks=0; ks<KS; ks++){
    #pragma unroll
    for (int kss=0; kss<2; kss++){
      const int k = kss*32 + lg*8;
      bf16x8 af[4], bfr[4];
      #pragma unroll
      for (int f=0;f<4;f++){
        int ra_ = wm*64 + f*16 + lr;
        af[f]  = *(const bf16x8*)(sA + buf*16384 + ra_*128 + ((k*2) ^ ((ra_&7)<<4)));
        int rb_ = wn*64 + f*16 + lr;
        bfr[f] = *(const bf16x8*)(sB + buf*16384 + rb_*128 + ((k*2) ^ ((rb_&7)<<4)));
      }
      #pragma unroll
      for (int fi=0;fi<4;fi++)
        #pragma unroll
        for (int fj=0;fj<4;fj++)
          acc[fi][fj] = __builtin_amdgcn_mfma_f32_16x16x32_bf16(af[fi], bfr[fj], acc[fi][fj], 0,0,0);
    }
    if (ks+1 < KS){
      writeregs(buf^1);                 // buf^1 safe: last read finished before prev barrier
      if (ks+2 < KS) loadregs(ks+2);    // issue next loads, land during next compute
    }
    __syncthreads();
    buf ^= 1;
  }
  #pragma unroll
  for (int fi=0;fi<4;fi++)
    #pragma unroll
    for (int fj=0;fj<4;fj++)
      #pragma unroll
      for (int j=0;j<4;j++){
        int m = m0 + wm*64 + fi*16 + lg*4 + j;
        int n = n0 + wn*64 + fj*16 + lr;
        int b = m / LOUT, t = m - b*LOUT;
        float val = fmaxf(acc[fi][fj][j] + bias[n], 0.f);
        if (TO_HCAT) out[(size_t)b*16640 + (size_t)n*64 + t] = f2bf(val);
        else         out[((size_t)b*(LOUT+2) + t + 1)*COUT + n] = f2bf(val);
      }
}

// ---------------- fc1: bf16 MFMA GEMM, K-split KZ, XCD-grouped, REG-STAGED dbuf ----------------
__global__ __launch_bounds__(256) void fc1_gemm_kernel(
    const unsigned short* __restrict__ A, const unsigned short* __restrict__ Bw,
    float* __restrict__ zp, int zoffm, int MT, int KZ){
  __shared__ __align__(16) char sA[2*128*128];
  __shared__ __align__(16) char sB[2*128*128];
  const int tid = threadIdx.x;
  const int nwg = gridDim.x;
  const int lgid = (blockIdx.x % 8)*(nwg/8) + blockIdx.x/8;
  const int kz  = lgid / (8*MT);
  const int rem = lgid % (8*MT);
  const int nt  = rem / MT;
  const int mt  = rem % MT;
  const int n0 = nt*128, m0 = mt*128;
  const int lane = tid & 63, wid = tid >> 6;
  const int wm = wid >> 1, wn = wid & 1;
  const int lr = lane & 15, lg = lane >> 4;
  const int srow = lane >> 3;
  const int ch = lane & 7;
  const unsigned short* abase[4];
  const unsigned short* bbase[4];
  int dsto[4];
  #pragma unroll
  for (int s=0;s<4;s++){
    int row = wid*32 + s*8 + srow;
    abase[s] = A  + (size_t)(m0+row)*16640 + ch*8;
    bbase[s] = Bw + (size_t)(n0+row)*16640 + ch*8;
    dsto[s] = row*128 + ((ch ^ srow) << 4);
  }
  f32x4 acc[4][4];
  #pragma unroll
  for (int i=0;i<4;i++)
    #pragma unroll
    for (int j=0;j<4;j++) acc[i][j] = (f32x4){0,0,0,0};
  const int it0 = (kz*260)/KZ, it1 = ((kz+1)*260)/KZ;

  ushort8 ra[4], rb[4];
  auto loadregs = [&](int it){
    const size_t k0 = (size_t)it*64;
    #pragma unroll
    for (int s=0;s<4;s++){
      ra[s] = *(const ushort8*)(abase[s] + k0);
      rb[s] = *(const ushort8*)(bbase[s] + k0);
    }
  };
  auto writeregs = [&](int bufi){
    #pragma unroll
    for (int s=0;s<4;s++){
      *(ushort8*)(sA + bufi*16384 + dsto[s]) = ra[s];
      *(ushort8*)(sB + bufi*16384 + dsto[s]) = rb[s];
    }
  };
  loadregs(it0); writeregs(0);
  if (it0+1 < it1) loadregs(it0+1);
  __syncthreads();
  int buf = 0;
  for (int it=it0; it<it1; ++it){
    #pragma unroll
    for (int ks=0; ks<2; ks++){
      const int k = ks*32 + lg*8;
      bf16x8 af[4], bfr[4];
      #pragma unroll
      for (int f=0;f<4;f++){
        int rowa = wm*64 + f*16 + lr;
        af[f]  = *(const bf16x8*)(sA + buf*16384 + rowa*128 + ((k*2) ^ ((rowa&7)<<4)));
        int rowb = wn*64 + f*16 + lr;
        bfr[f] = *(const bf16x8*)(sB + buf*16384 + rowb*128 + ((k*2) ^ ((rowb&7)<<4)));
      }
      #pragma unroll
      for (int fi=0;fi<4;fi++)
        #pragma unroll
        for (int fj=0;fj<4;fj++)
          acc[fi][fj] = __builtin_amdgcn_mfma_f32_16x16x32_bf16(af[fi], bfr[fj], acc[fi][fj], 0,0,0);
    }
    if (it+1 < it1){
      writeregs(buf^1);
      if (it+2 < it1) loadregs(it+2);
    }
    __syncthreads();
    buf ^= 1;
  }
  float* zo = zp + (size_t)kz*zoffm;
  #pragma unroll
  for (int fi=0;fi<4;fi++)
    #pragma unroll
    for (int fj=0;fj<4;fj++)
      #pragma unroll
      for (int j=0;j<4;j++){
        int m = m0 + wm*64 + fi*16 + lg*4 + j;
        int n = n0 + wn*64 + fj*16 + lr;
        zo[(size_t)m*1024 + n] = acc[fi][fj][j];
      }
}

// ---------------- fc2 ----------------
__global__ __launch_bounds__(256) void fc2_kernel(const float* __restrict__ zp, int zoffm, int KZ,
    const float* __restrict__ bfc1, const float* __restrict__ Wfc2,
    const float* __restrict__ bfc2, float* __restrict__ out){
  __shared__ float red[4][2];
  const int b = blockIdx.x, tid = threadIdx.x;
  float a0 = 0.f, a1 = 0.f;
  for (int n = tid; n < 1024; n += 256){
    float s = bfc1[n];
    const float* zb = zp + (size_t)b*1024 + n;
    for (int kz = 0; kz < KZ; kz++) s += zb[(size_t)kz*zoffm];
    s = fmaxf(s, 0.f);
    a0 = fmaf(s, Wfc2[n], a0);
    a1 = fmaf(s, Wfc2[1024+n], a1);
  }
  #pragma unroll
  for (int m=32; m>=1; m>>=1){ a0 += __shfl_xor(a0, m, 64); a1 += __shfl_xor(a1, m, 64); }
  const int w = tid >> 6;
  if ((tid & 63) == 0){ red[w][0] = a0; red[w][1] = a1; }
  __syncthreads();
  if (tid == 0){
    out[(size_t)b*2]   = red[0][0]+red[1][0]+red[2][0]+red[3][0] + bfc2[0];
    out[(size_t)b*2+1] = red[0][1]+red[1][1]+red[2][1]+red[3][1] + bfc2[1];
  }
}

extern "C" void kernel_launch(void* const* d_in, const int* in_sizes, int n_in,
                              void* d_out, int out_size, void* d_ws, size_t ws_size,
                              hipStream_t stream){
  const float* x    = (const float*)d_in[0];
  const float* Wp   = (const float*)d_in[1];
  const float* bp   = (const float*)d_in[2];
  const float* W1   = (const float*)d_in[3];
  const float* b1   = (const float*)d_in[4];
  const float* W2   = (const float*)d_in[5];
  const float* b2   = (const float*)d_in[6];
  const float* W3   = (const float*)d_in[7];
  const float* b3   = (const float*)d_in[8];
  const float* Wb1  = (const float*)d_in[9];
  const float* bb1  = (const float*)d_in[10];
  const float* Wb2  = (const float*)d_in[11];
  const float* bb2  = (const float*)d_in[12];
  const float* Wb3  = (const float*)d_in[13];
  const float* bb3  = (const float*)d_in[14];
  const float* Wfc1 = (const float*)d_in[15];
  const float* bfc1 = (const float*)d_in[16];
  const float* Wfc2 = (const float*)d_in[17];
  const float* bfc2 = (const float*)d_in[18];
  float* out = (float*)d_out;

  size_t off = 0;
  char* basep = (char*)d_ws;
  auto carve = [&](size_t bytes)->char*{
    char* q = basep + off; off += (bytes + 255) & ~(size_t)255; return q;
  };
  unsigned short* W1b   = (unsigned short*)carve((size_t)128*3*64*2);
  unsigned short* W2b   = (unsigned short*)carve((size_t)256*3*128*2);
  unsigned short* W3b   = (unsigned short*)carve((size_t)256*3*256*2);
  unsigned short* Bwp   = (unsigned short*)carve((size_t)64*128*2);
  unsigned short* Wfc1b = (unsigned short*)carve((size_t)1024*16640*2);
  size_t fixed = off;

  int Bc = 128, KZ = 64;
  {
    const int bcs[5] = {2048, 1024, 512, 256, 128};
    const int kzs[5] = {4, 8, 16, 32, 64};
    for (int i = 0; i < 5; i++){
      size_t b = bcs[i];
      size_t need = fixed + b*((size_t)66560+65792+33280) + (size_t)kzs[i]*b*4096 + 16*256;
      if (need <= ws_size){ Bc = bcs[i]; KZ = kzs[i]; break; }
    }
  }
  const int NC = 2048/Bc;
  const int MT = Bc/128;
  unsigned short* buf1 = (unsigned short*)carve((size_t)Bc*66560);
  unsigned short* buf2 = (unsigned short*)carve((size_t)Bc*65792);
  unsigned short* Hcat = (unsigned short*)carve((size_t)Bc*33280);
  float*          zp   = (float*)carve((size_t)KZ*Bc*4096);
  const int zoffm = Bc*1024;

  hipLaunchKernelGGL(pack_w_bf16_kernel, dim3((128*64*3+255)/256), dim3(256), 0, stream, W1, W1b, 128, 64);
  hipLaunchKernelGGL(pack_w_bf16_kernel, dim3((256*128*3+255)/256), dim3(256), 0, stream, W2, W2b, 256, 128);
  hipLaunchKernelGGL(pack_w_bf16_kernel, dim3((256*256*3+255)/256), dim3(256), 0, stream, W3, W3b, 256, 256);
  hipLaunchKernelGGL(pack_wp_kernel, dim3(32), dim3(256), 0, stream, Wp, Bwp);
  hipLaunchKernelGGL(f2bf_kernel, dim3((17039360+255)/256), dim3(256), 0, stream, Wfc1, Wfc1b, 17039360);

  for (int c = 0; c < NC; ++c){
    const float* xc = x + (size_t)c*Bc*16384;
    hipLaunchKernelGGL(zero_guards_kernel, dim3((Bc*2*64/8+255)/256), dim3(256), 0, stream,
                       buf1, 257, 64, Bc);
    hipLaunchKernelGGL(zero_guards_kernel, dim3((Bc*2*128/8+255)/256), dim3(256), 0, stream,
                       buf2, 257, 128, Bc);
    hipLaunchKernelGGL(branch_kernel, dim3(Bc), dim3(256), 0, stream,
                       xc, Wb1, bb1, Wb2, bb2, Wb3, bb3, Hcat);
    hipLaunchKernelGGL(h0_gemm_kernel, dim3(Bc*255/128), dim3(256), 0, stream, xc, Bwp, bp, buf1);
    // conv1: 64->128, S=1, padded 257 -> padded 257x128 ; M = Bc*255
    hipLaunchKernelGGL((conv_gemm_kernel<64,128,1,257,255,false>), dim3(Bc*255/128, 1), dim3(256), 0, stream,
                       buf1, W1b, b1, buf2);
    hipLaunchKernelGGL(zero_guards_kernel, dim3((Bc*2*256/8+255)/256), dim3(256), 0, stream,
                       buf1, 130, 256, Bc);
    // conv2: 128->256, S=2, padded 257 -> padded 130x256 ; M = Bc*128
    hipLaunchKernelGGL((conv_gemm_kernel<128,256,2,257,128,false>), dim3(Bc, 2), dim3(256), 0, stream,
                       buf2, W2b, b2, buf1);
    // conv3: 256->256, S=2, padded 130 -> Hcat channel-major ; M = Bc*64
    hipLaunchKernelGGL((conv_gemm_kernel<256,256,2,130,64,true>), dim3(Bc/2, 2), dim3(256), 0, stream,
                       buf1, W3b, b3, Hcat);
    hipLaunchKernelGGL(fc1_gemm_kernel, dim3(8*MT*KZ), dim3(256), 0, stream,
                       Hcat, Wfc1b, zp, zoffm, MT, KZ);
    hipLaunchKernelGGL(fc2_kernel, dim3(Bc), dim3(256), 0, stream,
                       zp, zoffm, KZ, bfc1, Wfc2, bfc2, out + (size_t)c*Bc*2);
  }
}

// Round 17
// 545.874 us; speedup vs baseline: 1.0551x; 1.0026x over previous
//
#include <hip/hip_runtime.h>
#include <cstdint>
#include <cstddef>

typedef __attribute__((ext_vector_type(8))) short bf16x8;
typedef __attribute__((ext_vector_type(8))) unsigned short ushort8;
typedef __attribute__((ext_vector_type(4))) float f32x4;

__device__ __forceinline__ unsigned short f2bf(float f){
  unsigned int u = __float_as_uint(f);
  unsigned int lsb = (u >> 16) & 1u;
  u += 0x7fffu + lsb;
  return (unsigned short)(u >> 16);
}

// ---------------- weight packing ----------------
__global__ __launch_bounds__(256) void pack_w_bf16_kernel(const float* __restrict__ W,
    unsigned short* __restrict__ Wb, int COUT, int CIN){
  int idx = blockIdx.x*256 + threadIdx.x;
  int tot = COUT*CIN*3;
  if (idx >= tot) return;
  int o = idx/(CIN*3); int r = idx - o*(CIN*3); int kk = r/CIN; int ci = r - kk*CIN;
  Wb[idx] = f2bf(W[(o*CIN + ci)*3 + kk]);
}

__global__ __launch_bounds__(256) void pack_wp_kernel(const float* __restrict__ Wp,
                                                      unsigned short* __restrict__ Bw){
  int idx = blockIdx.x*256 + threadIdx.x;
  if (idx >= 64*128) return;
  int p = idx >> 7, k = idx & 127;
  float v = (k < 64) ? Wp[p*128 + k*2] : Wp[p*128 + (k-64)*2 + 1];
  Bw[idx] = f2bf(v);
}

__global__ __launch_bounds__(256) void f2bf_kernel(const float* __restrict__ src,
                                                   unsigned short* __restrict__ dst, int n){
  int i = blockIdx.x*256 + threadIdx.x;
  if (i < n) dst[i] = f2bf(src[i]);
}

// zero guard rows 0 and LINP-1 of each padded batch
__global__ __launch_bounds__(256) void zero_guards_kernel(unsigned short* __restrict__ buf,
                                                          int LINP, int CIN, int nb){
  int idx = blockIdx.x*256 + threadIdx.x;
  int per = 2*CIN/8;
  if (idx >= nb*per) return;
  int b = idx / per, r = idx - b*per;
  int g = r / (CIN/8), c8 = r - g*(CIN/8);
  ushort8 z = {0,0,0,0,0,0,0,0};
  *(ushort8*)(buf + ((size_t)b*LINP + (size_t)g*(LINP-1))*CIN + c8*8) = z;
}

// ---------------- branch MLP -> Hcat[16384:] ----------------
__global__ __launch_bounds__(256) void branch_kernel(const float* __restrict__ x,
    const float* __restrict__ Wb1, const float* __restrict__ bb1,
    const float* __restrict__ Wb2, const float* __restrict__ bb2,
    const float* __restrict__ Wb3, const float* __restrict__ bb3,
    unsigned short* __restrict__ Hcat){
  __shared__ float s0[64], s1[64], s2[128];
  const int b = blockIdx.x, tid = threadIdx.x;
  const float* xb = x + (size_t)b*16384;
  if (tid < 64) s0[tid] = xb[tid];
  __syncthreads();
  if (tid < 64){
    float a = bb1[tid];
    for (int k=0;k<64;k++) a = fmaf(Wb1[tid*64+k], s0[k], a);
    s1[tid] = fmaxf(a, 0.f);
  }
  __syncthreads();
  if (tid < 128){
    float a = bb2[tid];
    for (int k=0;k<64;k++) a = fmaf(Wb2[tid*64+k], s1[k], a);
    s2[tid] = fmaxf(a, 0.f);
  }
  __syncthreads();
  float a = bb3[tid];
  for (int k=0;k<128;k++) a = fmaf(Wb3[tid*128+k], s2[k], a);
  Hcat[(size_t)b*16640 + 16384 + tid] = f2bf(fmaxf(a, 0.f));
}

// ---------------- h0 GEMM -> padded [b][257][64] ----------------
__global__ __launch_bounds__(256) void h0_gemm_kernel(const float* __restrict__ x,
    const unsigned short* __restrict__ Bw, const float* __restrict__ bp,
    unsigned short* __restrict__ h0o){
  __shared__ __align__(16) char sAraw[128*256];
  __shared__ __align__(16) char sBraw[64*256];
  const int tid = threadIdx.x;
  const int m0 = blockIdx.x*128;
  #pragma unroll
  for (int i=0;i<16;i++){
    int j = tid + 256*i;
    int row = j >> 5, q = j & 31;
    int m = m0 + row;
    int b = m / 255, c = m - b*255;
    const float* xb = x + (size_t)b*16384;
    int k = q*4;
    const float* src = (k < 64) ? (xb + k) : (xb + (c+1)*64 + (k-64));
    float4 v = *(const float4*)src;
    ushort4 u; u.x=f2bf(v.x); u.y=f2bf(v.y); u.z=f2bf(v.z); u.w=f2bf(v.w);
    *(ushort4*)(sAraw + row*256 + ((k*2) ^ ((row&7)<<4))) = u;
  }
  #pragma unroll
  for (int i=0;i<4;i++){
    int j = tid + 256*i;
    int row = j >> 4, q = j & 15;
    int k = q*8;
    ushort8 u = *(const ushort8*)(Bw + row*128 + k);
    *(ushort8*)(sBraw + row*256 + ((k*2) ^ ((row&7)<<4))) = u;
  }
  __syncthreads();
  const int lane = tid & 63, wid = tid >> 6;
  const int lr = lane & 15, lg = lane >> 4;
  f32x4 acc[2][4];
  #pragma unroll
  for (int a=0;a<2;a++)
    #pragma unroll
    for (int j=0;j<4;j++) acc[a][j] = (f32x4){0,0,0,0};
  #pragma unroll
  for (int ks=0; ks<4; ks++){
    int k = ks*32 + lg*8;
    bf16x8 af[2], bfr[4];
    #pragma unroll
    for (int f=0; f<2; f++){
      int row = wid*32 + f*16 + lr;
      af[f] = *(const bf16x8*)(sAraw + row*256 + ((k*2) ^ ((row&7)<<4)));
    }
    #pragma unroll
    for (int f=0; f<4; f++){
      int row = f*16 + lr;
      bfr[f] = *(const bf16x8*)(sBraw + row*256 + ((k*2) ^ ((row&7)<<4)));
    }
    #pragma unroll
    for (int fi=0; fi<2; fi++)
      #pragma unroll
      for (int fj=0; fj<4; fj++)
        acc[fi][fj] = __builtin_amdgcn_mfma_f32_16x16x32_bf16(af[fi], bfr[fj], acc[fi][fj], 0,0,0);
  }
  #pragma unroll
  for (int fi=0; fi<2; fi++)
    #pragma unroll
    for (int fj=0; fj<4; fj++)
      #pragma unroll
      for (int j=0;j<4;j++){
        int m = m0 + wid*32 + fi*16 + lg*4 + j;
        int n = fj*16 + lr;
        int b = m / 255, t = m - b*255;
        h0o[((size_t)b*257 + t + 1)*64 + n] = f2bf(fmaxf(acc[fi][fj][j] + bp[n], 0.f));
      }
}

// ---------------- conv1d as plain GEMM, REG-STAGED (L1/L2-cached) dbuf K-pipeline ----------------
// lane loads logical 16B chunk (lane&7) linearly (coalesced), ds_writes to swizzled slot chunk^(row&7).
template<int CIN,int COUT,int S,int LINP,int LOUT,bool TO_HCAT>
__global__ __launch_bounds__(256) void conv_gemm_kernel(
    const unsigned short* __restrict__ in, const unsigned short* __restrict__ Wb,
    const float* __restrict__ bias, unsigned short* __restrict__ out){
  constexpr int K = 3*CIN;
  constexpr int KS = K/64;
  __shared__ __align__(16) char sA[2*128*128];
  __shared__ __align__(16) char sB[2*128*128];
  const int tid = threadIdx.x;
  int m0;
  {
    int bid = blockIdx.x, nwg = gridDim.x;
    if ((nwg & 7) == 0){ int q = nwg >> 3; m0 = ((bid & 7)*q + (bid >> 3))*128; }
    else m0 = bid*128;
  }
  const int n0 = blockIdx.y*128;
  const int lane = tid & 63, wid = tid >> 6;
  const int wm = wid >> 1, wn = wid & 1;
  const int lr = lane & 15, lg = lane >> 4;
  const int srow = lane >> 3;
  const int ch = lane & 7;
  const unsigned short* abase[4];
  const unsigned short* bbase[4];
  int dsto[4];
  #pragma unroll
  for (int s=0;s<4;s++){
    int row = wid*32 + s*8 + srow;
    int m = m0 + row;
    int b = m / LOUT, t = m - b*LOUT;
    abase[s] = in + ((size_t)b*LINP + (size_t)t*S)*CIN + ch*8;
    bbase[s] = Wb + (size_t)(n0+row)*K + ch*8;
    dsto[s] = row*128 + ((ch ^ srow) << 4);
  }
  f32x4 acc[4][4];
  #pragma unroll
  for (int i=0;i<4;i++)
    #pragma unroll
    for (int j=0;j<4;j++) acc[i][j] = (f32x4){0,0,0,0};

  ushort8 ra[4], rb[4];
  auto loadregs = [&](int ks){
    const int k0 = ks*64;
    #pragma unroll
    for (int s=0;s<4;s++){
      ra[s] = *(const ushort8*)(abase[s] + k0);
      rb[s] = *(const ushort8*)(bbase[s] + k0);
    }
  };
  auto writeregs = [&](int bufi){
    #pragma unroll
    for (int s=0;s<4;s++){
      *(ushort8*)(sA + bufi*16384 + dsto[s]) = ra[s];
      *(ushort8*)(sB + bufi*16384 + dsto[s]) = rb[s];
    }
  };
  loadregs(0); writeregs(0);
  if (KS > 1) loadregs(1);
  __syncthreads();
  int buf = 0;
  #pragma unroll
  for (int ks=0; ks<KS; ks++){
    #pragma unroll
    for (int kss=0; kss<2; kss++){
      const int k = kss*32 + lg*8;
      bf16x8 af[4], bfr[4];
      #pragma unroll
      for (int f=0;f<4;f++){
        int ra_ = wm*64 + f*16 + lr;
        af[f]  = *(const bf16x8*)(sA + buf*16384 + ra_*128 + ((k*2) ^ ((ra_&7)<<4)));
        int rb_ = wn*64 + f*16 + lr;
        bfr[f] = *(const bf16x8*)(sB + buf*16384 + rb_*128 + ((k*2) ^ ((rb_&7)<<4)));
      }
      #pragma unroll
      for (int fi=0;fi<4;fi++)
        #pragma unroll
        for (int fj=0;fj<4;fj++)
          acc[fi][fj] = __builtin_amdgcn_mfma_f32_16x16x32_bf16(af[fi], bfr[fj], acc[fi][fj], 0,0,0);
    }
    if (ks+1 < KS){
      writeregs(buf^1);                 // buf^1 safe: last read finished before prev barrier
      if (ks+2 < KS) loadregs(ks+2);    // issue next loads, land during next compute
    }
    __syncthreads();
    buf ^= 1;
  }
  #pragma unroll
  for (int fi=0;fi<4;fi++)
    #pragma unroll
    for (int fj=0;fj<4;fj++)
      #pragma unroll
      for (int j=0;j<4;j++){
        int m = m0 + wm*64 + fi*16 + lg*4 + j;
        int n = n0 + wn*64 + fj*16 + lr;
        int b = m / LOUT, t = m - b*LOUT;
        float val = fmaxf(acc[fi][fj][j] + bias[n], 0.f);
        if (TO_HCAT) out[(size_t)b*16640 + (size_t)n*64 + t] = f2bf(val);
        else         out[((size_t)b*(LOUT+2) + t + 1)*COUT + n] = f2bf(val);
      }
}

// ---------------- fc1: bf16 MFMA GEMM, K-split KZ, XCD-grouped, REG-STAGED dbuf ----------------
__global__ __launch_bounds__(256) void fc1_gemm_kernel(
    const unsigned short* __restrict__ A, const unsigned short* __restrict__ Bw,
    float* __restrict__ zp, int zoffm, int MT, int KZ){
  __shared__ __align__(16) char sA[2*128*128];
  __shared__ __align__(16) char sB[2*128*128];
  const int tid = threadIdx.x;
  const int nwg = gridDim.x;
  const int lgid = (blockIdx.x % 8)*(nwg/8) + blockIdx.x/8;
  const int kz  = lgid / (8*MT);
  const int rem = lgid % (8*MT);
  const int nt  = rem / MT;
  const int mt  = rem % MT;
  const int n0 = nt*128, m0 = mt*128;
  const int lane = tid & 63, wid = tid >> 6;
  const int wm = wid >> 1, wn = wid & 1;
  const int lr = lane & 15, lg = lane >> 4;
  const int srow = lane >> 3;
  const int ch = lane & 7;
  const unsigned short* abase[4];
  const unsigned short* bbase[4];
  int dsto[4];
  #pragma unroll
  for (int s=0;s<4;s++){
    int row = wid*32 + s*8 + srow;
    abase[s] = A  + (size_t)(m0+row)*16640 + ch*8;
    bbase[s] = Bw + (size_t)(n0+row)*16640 + ch*8;
    dsto[s] = row*128 + ((ch ^ srow) << 4);
  }
  f32x4 acc[4][4];
  #pragma unroll
  for (int i=0;i<4;i++)
    #pragma unroll
    for (int j=0;j<4;j++) acc[i][j] = (f32x4){0,0,0,0};
  const int it0 = (kz*260)/KZ, it1 = ((kz+1)*260)/KZ;

  ushort8 ra[4], rb[4];
  auto loadregs = [&](int it){
    const size_t k0 = (size_t)it*64;
    #pragma unroll
    for (int s=0;s<4;s++){
      ra[s] = *(const ushort8*)(abase[s] + k0);
      rb[s] = *(const ushort8*)(bbase[s] + k0);
    }
  };
  auto writeregs = [&](int bufi){
    #pragma unroll
    for (int s=0;s<4;s++){
      *(ushort8*)(sA + bufi*16384 + dsto[s]) = ra[s];
      *(ushort8*)(sB + bufi*16384 + dsto[s]) = rb[s];
    }
  };
  loadregs(it0); writeregs(0);
  if (it0+1 < it1) loadregs(it0+1);
  __syncthreads();
  int buf = 0;
  for (int it=it0; it<it1; ++it){
    #pragma unroll
    for (int ks=0; ks<2; ks++){
      const int k = ks*32 + lg*8;
      bf16x8 af[4], bfr[4];
      #pragma unroll
      for (int f=0;f<4;f++){
        int rowa = wm*64 + f*16 + lr;
        af[f]  = *(const bf16x8*)(sA + buf*16384 + rowa*128 + ((k*2) ^ ((rowa&7)<<4)));
        int rowb = wn*64 + f*16 + lr;
        bfr[f] = *(const bf16x8*)(sB + buf*16384 + rowb*128 + ((k*2) ^ ((rowb&7)<<4)));
      }
      #pragma unroll
      for (int fi=0;fi<4;fi++)
        #pragma unroll
        for (int fj=0;fj<4;fj++)
          acc[fi][fj] = __builtin_amdgcn_mfma_f32_16x16x32_bf16(af[fi], bfr[fj], acc[fi][fj], 0,0,0);
    }
    if (it+1 < it1){
      writeregs(buf^1);
      if (it+2 < it1) loadregs(it+2);
    }
    __syncthreads();
    buf ^= 1;
  }
  float* zo = zp + (size_t)kz*zoffm;
  #pragma unroll
  for (int fi=0;fi<4;fi++)
    #pragma unroll
    for (int fj=0;fj<4;fj++)
      #pragma unroll
      for (int j=0;j<4;j++){
        int m = m0 + wm*64 + fi*16 + lg*4 + j;
        int n = n0 + wn*64 + fj*16 + lr;
        zo[(size_t)m*1024 + n] = acc[fi][fj][j];
      }
}

// ---------------- fc2 ----------------
__global__ __launch_bounds__(256) void fc2_kernel(const float* __restrict__ zp, int zoffm, int KZ,
    const float* __restrict__ bfc1, const float* __restrict__ Wfc2,
    const float* __restrict__ bfc2, float* __restrict__ out){
  __shared__ float red[4][2];
  const int b = blockIdx.x, tid = threadIdx.x;
  float a0 = 0.f, a1 = 0.f;
  for (int n = tid; n < 1024; n += 256){
    float s = bfc1[n];
    const float* zb = zp + (size_t)b*1024 + n;
    for (int kz = 0; kz < KZ; kz++) s += zb[(size_t)kz*zoffm];
    s = fmaxf(s, 0.f);
    a0 = fmaf(s, Wfc2[n], a0);
    a1 = fmaf(s, Wfc2[1024+n], a1);
  }
  #pragma unroll
  for (int m=32; m>=1; m>>=1){ a0 += __shfl_xor(a0, m, 64); a1 += __shfl_xor(a1, m, 64); }
  const int w = tid >> 6;
  if ((tid & 63) == 0){ red[w][0] = a0; red[w][1] = a1; }
  __syncthreads();
  if (tid == 0){
    out[(size_t)b*2]   = red[0][0]+red[1][0]+red[2][0]+red[3][0] + bfc2[0];
    out[(size_t)b*2+1] = red[0][1]+red[1][1]+red[2][1]+red[3][1] + bfc2[1];
  }
}

extern "C" void kernel_launch(void* const* d_in, const int* in_sizes, int n_in,
                              void* d_out, int out_size, void* d_ws, size_t ws_size,
                              hipStream_t stream){
  const float* x    = (const float*)d_in[0];
  const float* Wp   = (const float*)d_in[1];
  const float* bp   = (const float*)d_in[2];
  const float* W1   = (const float*)d_in[3];
  const float* b1   = (const float*)d_in[4];
  const float* W2   = (const float*)d_in[5];
  const float* b2   = (const float*)d_in[6];
  const float* W3   = (const float*)d_in[7];
  const float* b3   = (const float*)d_in[8];
  const float* Wb1  = (const float*)d_in[9];
  const float* bb1  = (const float*)d_in[10];
  const float* Wb2  = (const float*)d_in[11];
  const float* bb2  = (const float*)d_in[12];
  const float* Wb3  = (const float*)d_in[13];
  const float* bb3  = (const float*)d_in[14];
  const float* Wfc1 = (const float*)d_in[15];
  const float* bfc1 = (const float*)d_in[16];
  const float* Wfc2 = (const float*)d_in[17];
  const float* bfc2 = (const float*)d_in[18];
  float* out = (float*)d_out;

  size_t off = 0;
  char* basep = (char*)d_ws;
  auto carve = [&](size_t bytes)->char*{
    char* q = basep + off; off += (bytes + 255) & ~(size_t)255; return q;
  };
  unsigned short* W1b   = (unsigned short*)carve((size_t)128*3*64*2);
  unsigned short* W2b   = (unsigned short*)carve((size_t)256*3*128*2);
  unsigned short* W3b   = (unsigned short*)carve((size_t)256*3*256*2);
  unsigned short* Bwp   = (unsigned short*)carve((size_t)64*128*2);
  unsigned short* Wfc1b = (unsigned short*)carve((size_t)1024*16640*2);
  size_t fixed = off;

  int Bc = 128, KZ = 64;
  {
    const int bcs[5] = {2048, 1024, 512, 256, 128};
    const int kzs[5] = {4, 8, 16, 32, 64};
    for (int i = 0; i < 5; i++){
      size_t b = bcs[i];
      size_t need = fixed + b*((size_t)66560+65792+33280) + (size_t)kzs[i]*b*4096 + 16*256;
      if (need <= ws_size){ Bc = bcs[i]; KZ = kzs[i]; break; }
    }
  }
  const int NC = 2048/Bc;
  const int MT = Bc/128;
  unsigned short* buf1 = (unsigned short*)carve((size_t)Bc*66560);
  unsigned short* buf2 = (unsigned short*)carve((size_t)Bc*65792);
  unsigned short* Hcat = (unsigned short*)carve((size_t)Bc*33280);
  float*          zp   = (float*)carve((size_t)KZ*Bc*4096);
  const int zoffm = Bc*1024;

  hipLaunchKernelGGL(pack_w_bf16_kernel, dim3((128*64*3+255)/256), dim3(256), 0, stream, W1, W1b, 128, 64);
  hipLaunchKernelGGL(pack_w_bf16_kernel, dim3((256*128*3+255)/256), dim3(256), 0, stream, W2, W2b, 256, 128);
  hipLaunchKernelGGL(pack_w_bf16_kernel, dim3((256*256*3+255)/256), dim3(256), 0, stream, W3, W3b, 256, 256);
  hipLaunchKernelGGL(pack_wp_kernel, dim3(32), dim3(256), 0, stream, Wp, Bwp);
  hipLaunchKernelGGL(f2bf_kernel, dim3((17039360+255)/256), dim3(256), 0, stream, Wfc1, Wfc1b, 17039360);

  for (int c = 0; c < NC; ++c){
    const float* xc = x + (size_t)c*Bc*16384;
    hipLaunchKernelGGL(zero_guards_kernel, dim3((Bc*2*64/8+255)/256), dim3(256), 0, stream,
                       buf1, 257, 64, Bc);
    hipLaunchKernelGGL(zero_guards_kernel, dim3((Bc*2*128/8+255)/256), dim3(256), 0, stream,
                       buf2, 257, 128, Bc);
    hipLaunchKernelGGL(branch_kernel, dim3(Bc), dim3(256), 0, stream,
                       xc, Wb1, bb1, Wb2, bb2, Wb3, bb3, Hcat);
    hipLaunchKernelGGL(h0_gemm_kernel, dim3(Bc*255/128), dim3(256), 0, stream, xc, Bwp, bp, buf1);
    // conv1: 64->128, S=1, padded 257 -> padded 257x128 ; M = Bc*255
    hipLaunchKernelGGL((conv_gemm_kernel<64,128,1,257,255,false>), dim3(Bc*255/128, 1), dim3(256), 0, stream,
                       buf1, W1b, b1, buf2);
    hipLaunchKernelGGL(zero_guards_kernel, dim3((Bc*2*256/8+255)/256), dim3(256), 0, stream,
                       buf1, 130, 256, Bc);
    // conv2: 128->256, S=2, padded 257 -> padded 130x256 ; M = Bc*128
    hipLaunchKernelGGL((conv_gemm_kernel<128,256,2,257,128,false>), dim3(Bc, 2), dim3(256), 0, stream,
                       buf2, W2b, b2, buf1);
    // conv3: 256->256, S=2, padded 130 -> Hcat channel-major ; M = Bc*64
    hipLaunchKernelGGL((conv_gemm_kernel<256,256,2,130,64,true>), dim3(Bc/2, 2), dim3(256), 0, stream,
                       buf1, W3b, b3, Hcat);
    hipLaunchKernelGGL(fc1_gemm_kernel, dim3(8*MT*KZ), dim3(256), 0, stream,
                       Hcat, Wfc1b, zp, zoffm, MT, KZ);
    hipLaunchKernelGGL(fc2_kernel, dim3(Bc), dim3(256), 0, stream,
                       zp, zoffm, KZ, bfc1, Wfc2, bfc2, out + (size_t)c*Bc*2);
  }
}